// Round 1
// 766.554 us; speedup vs baseline: 1.0732x; 1.0732x over previous
//
#include <hip/hip_runtime.h>
#include <math.h>

// ---------------------------------------------------------------------------
// LocalWinCrossAttnOcc: pool -> qkv proj + GN -> 7x7 window attn w/ occ bias
//                       -> Wo proj * clip(occ) -> bilinear x4 -> residual add
// Shapes: B=2, C_IMG=256, C_RAD=128, H=W=384, D=64, h=w=96, P=49
// ---------------------------------------------------------------------------

namespace {
constexpr int HIN  = 384;
constexpr int WIN_ = 384;
constexpr int HP   = 96;
constexpr int WPX  = 96;
constexpr int NP   = HP * WPX;      // 9216
constexpr int CIMG = 256;
constexpr int CRAD = 128;
constexpr int DD   = 64;
constexpr int BB   = 2;
constexpr float OOB_LOGIT = -27.631021115928547f;  // 2*ln(1e-6)

// workspace offsets (in floats)
constexpr size_t OFF_IMGP = 0;                                    // [B][256][9216]
constexpr size_t OFF_RADP = OFF_IMGP + (size_t)BB * CIMG * NP;    // [B][128][9216]
constexpr size_t OFF_OCCP = OFF_RADP + (size_t)BB * CRAD * NP;    // [B][9216]
constexpr size_t OFF_OCCL = OFF_OCCP + (size_t)BB * NP;           // [B][9216]
constexpr size_t OFF_Q    = OFF_OCCL + (size_t)BB * NP;           // [B][9216][64]
constexpr size_t OFF_K    = OFF_Q + (size_t)BB * NP * DD;
constexpr size_t OFF_V    = OFF_K + (size_t)BB * NP * DD;
constexpr size_t OFF_MSG  = OFF_V + (size_t)BB * NP * DD;         // [B][9216][64]
constexpr size_t OFF_MSGO = OFF_MSG + (size_t)BB * NP * DD;       // [B][256][9216]
constexpr size_t OFF_WOT  = OFF_MSGO + (size_t)BB * CIMG * NP;    // [64][256]
constexpr size_t OFF_STAT = OFF_WOT + (size_t)DD * CIMG;          // q:32, k:32
constexpr size_t OFF_COEF = OFF_STAT + 64;                        // aq,bq,ak,bk: 4*128
}  // namespace

// ---------------------------------------------------------------------------
// Kernel 1: 4x4 pooling (img avg, rad max, occ max + occ log)
// ---------------------------------------------------------------------------
__global__ __launch_bounds__(256) void pool_kernel(const float* __restrict__ img,
                                                   const float* __restrict__ rad,
                                                   const float* __restrict__ occ,
                                                   float* __restrict__ ws) {
  int bid = blockIdx.x;
  int tid = threadIdx.x;
  const float* src;
  float* dst;
  float* occl = nullptr;
  int mode;  // 0 avg, 1 max, 2 max+log
  if (bid < BB * CIMG) {
    src = img + (size_t)bid * HIN * WIN_;
    dst = ws + OFF_IMGP + (size_t)bid * NP;
    mode = 0;
  } else if (bid < BB * CIMG + BB * CRAD) {
    int r = bid - BB * CIMG;
    src = rad + (size_t)r * HIN * WIN_;
    dst = ws + OFF_RADP + (size_t)r * NP;
    mode = 1;
  } else {
    int r = bid - BB * CIMG - BB * CRAD;
    src = occ + (size_t)r * HIN * WIN_;
    dst = ws + OFF_OCCP + (size_t)r * NP;
    occl = ws + OFF_OCCL + (size_t)r * NP;
    mode = 2;
  }
  for (int it = 0; it < NP / 256; ++it) {
    int idx = it * 256 + tid;
    int oy = idx / WPX, ox = idx % WPX;
    const float* p = src + (size_t)(oy * 4) * WIN_ + ox * 4;
    if (mode == 0) {
      float s = 0.f;
#pragma unroll
      for (int r = 0; r < 4; ++r) {
        float4 v = *(const float4*)(p + (size_t)r * WIN_);
        s += v.x + v.y + v.z + v.w;
      }
      dst[idx] = s * 0.0625f;
    } else {
      float m = -INFINITY;
#pragma unroll
      for (int r = 0; r < 4; ++r) {
        float4 v = *(const float4*)(p + (size_t)r * WIN_);
        m = fmaxf(m, fmaxf(fmaxf(v.x, v.y), fmaxf(v.z, v.w)));
      }
      dst[idx] = m;
      if (mode == 2) occl[idx] = 2.0f * logf(fmaxf(m, 1e-6f));
    }
  }
}

// ---------------------------------------------------------------------------
// Kernel 2 (merged): q = Wq @ img_pool (C=256)  OR  k,v = Wk,Wv @ rad_pool
// (C=128), layout [b][n][64], + GN stats (atomics).
// grid: 2 * B * (NP/64) = 576 blocks, 256 threads. bid<288 -> q path.
// Merging doubles CU occupancy vs two serialized 288-block launches.
// ---------------------------------------------------------------------------
__global__ __launch_bounds__(256) void proj_kernel(const float* __restrict__ Wq,
                                                   const float* __restrict__ Wk,
                                                   const float* __restrict__ Wv,
                                                   float* __restrict__ ws) {
  __shared__ float smem[3 * 32 * 64 + 16];
  float* Xs = smem;          // 32*64
  float* Wa = smem + 2048;   // 32*64
  float* Wb = smem + 4096;   // 32*64 (kv path only)
  float* sstat = smem + 6144;
  int bid = blockIdx.x;
  int tid = threadIdx.x;
  int og = tid & 15, ng = tid >> 4;
  if (tid < 16) sstat[tid] = 0.f;
  const int NBLK = BB * (NP / 64);  // 288

  if (bid < NBLK) {
    // ---- Q path: C = 256 ----
    int b = bid / (NP / 64);
    int n0 = (bid % (NP / 64)) * 64;
    float4 acc[4];
#pragma unroll
    for (int j = 0; j < 4; ++j) acc[j] = make_float4(0.f, 0.f, 0.f, 0.f);
    const float* X = ws + OFF_IMGP + (size_t)b * CIMG * NP;
    for (int c0 = 0; c0 < CIMG; c0 += 32) {
      {
        int cc = tid >> 3, seg = tid & 7;
        const float* g = X + (size_t)(c0 + cc) * NP + n0 + seg * 8;
        float4 a0 = *(const float4*)g;
        float4 a1 = *(const float4*)(g + 4);
        *(float4*)&Xs[cc * 64 + seg * 8] = a0;
        *(float4*)&Xs[cc * 64 + seg * 8 + 4] = a1;
      }
      {
        int o = tid & 63, q8 = tid >> 6;
        const float* g = Wq + (size_t)o * CIMG + c0 + q8 * 8;
        float4 a0 = *(const float4*)g;
        float4 a1 = *(const float4*)(g + 4);
        Wa[(q8 * 8 + 0) * 64 + o] = a0.x;
        Wa[(q8 * 8 + 1) * 64 + o] = a0.y;
        Wa[(q8 * 8 + 2) * 64 + o] = a0.z;
        Wa[(q8 * 8 + 3) * 64 + o] = a0.w;
        Wa[(q8 * 8 + 4) * 64 + o] = a1.x;
        Wa[(q8 * 8 + 5) * 64 + o] = a1.y;
        Wa[(q8 * 8 + 6) * 64 + o] = a1.z;
        Wa[(q8 * 8 + 7) * 64 + o] = a1.w;
      }
      __syncthreads();
#pragma unroll
      for (int cc = 0; cc < 32; ++cc) {
        float4 wv = *(const float4*)&Wa[cc * 64 + og * 4];
        float4 xv = *(const float4*)&Xs[cc * 64 + ng * 4];
        acc[0].x = fmaf(wv.x, xv.x, acc[0].x); acc[0].y = fmaf(wv.y, xv.x, acc[0].y);
        acc[0].z = fmaf(wv.z, xv.x, acc[0].z); acc[0].w = fmaf(wv.w, xv.x, acc[0].w);
        acc[1].x = fmaf(wv.x, xv.y, acc[1].x); acc[1].y = fmaf(wv.y, xv.y, acc[1].y);
        acc[1].z = fmaf(wv.z, xv.y, acc[1].z); acc[1].w = fmaf(wv.w, xv.y, acc[1].w);
        acc[2].x = fmaf(wv.x, xv.z, acc[2].x); acc[2].y = fmaf(wv.y, xv.z, acc[2].y);
        acc[2].z = fmaf(wv.z, xv.z, acc[2].z); acc[2].w = fmaf(wv.w, xv.z, acc[2].w);
        acc[3].x = fmaf(wv.x, xv.w, acc[3].x); acc[3].y = fmaf(wv.y, xv.w, acc[3].y);
        acc[3].z = fmaf(wv.z, xv.w, acc[3].z); acc[3].w = fmaf(wv.w, xv.w, acc[3].w);
      }
      __syncthreads();
    }
    float* outq = ws + OFF_Q + (size_t)b * NP * DD;
#pragma unroll
    for (int j = 0; j < 4; ++j) {
      *(float4*)&outq[(size_t)(n0 + ng * 4 + j) * DD + og * 4] = acc[j];
    }
    float s1 = 0.f, s2 = 0.f;
#pragma unroll
    for (int j = 0; j < 4; ++j) {
      s1 += acc[j].x + acc[j].y + acc[j].z + acc[j].w;
      s2 += acc[j].x * acc[j].x + acc[j].y * acc[j].y + acc[j].z * acc[j].z +
            acc[j].w * acc[j].w;
    }
    int g = og >> 1;
    atomicAdd(&sstat[g * 2], s1);
    atomicAdd(&sstat[g * 2 + 1], s2);
    __syncthreads();
    if (tid < 16) atomicAdd(&ws[OFF_STAT + b * 16 + tid], sstat[tid]);
  } else {
    // ---- KV path: C = 128 ----
    int r = bid - NBLK;
    int b = r / (NP / 64);
    int n0 = (r % (NP / 64)) * 64;
    float4 acck[4], accv[4];
#pragma unroll
    for (int j = 0; j < 4; ++j) {
      acck[j] = make_float4(0.f, 0.f, 0.f, 0.f);
      accv[j] = make_float4(0.f, 0.f, 0.f, 0.f);
    }
    const float* X = ws + OFF_RADP + (size_t)b * CRAD * NP;
    for (int c0 = 0; c0 < CRAD; c0 += 32) {
      {
        int cc = tid >> 3, seg = tid & 7;
        const float* g = X + (size_t)(c0 + cc) * NP + n0 + seg * 8;
        float4 a0 = *(const float4*)g;
        float4 a1 = *(const float4*)(g + 4);
        *(float4*)&Xs[cc * 64 + seg * 8] = a0;
        *(float4*)&Xs[cc * 64 + seg * 8 + 4] = a1;
      }
      {
        int o = tid & 63, q8 = tid >> 6;
        const float* gk = Wk + (size_t)o * CRAD + c0 + q8 * 8;
        const float* gv = Wv + (size_t)o * CRAD + c0 + q8 * 8;
        float4 k0 = *(const float4*)gk;
        float4 k1 = *(const float4*)(gk + 4);
        float4 v0 = *(const float4*)gv;
        float4 v1 = *(const float4*)(gv + 4);
        Wa[(q8 * 8 + 0) * 64 + o] = k0.x; Wa[(q8 * 8 + 1) * 64 + o] = k0.y;
        Wa[(q8 * 8 + 2) * 64 + o] = k0.z; Wa[(q8 * 8 + 3) * 64 + o] = k0.w;
        Wa[(q8 * 8 + 4) * 64 + o] = k1.x; Wa[(q8 * 8 + 5) * 64 + o] = k1.y;
        Wa[(q8 * 8 + 6) * 64 + o] = k1.z; Wa[(q8 * 8 + 7) * 64 + o] = k1.w;
        Wb[(q8 * 8 + 0) * 64 + o] = v0.x; Wb[(q8 * 8 + 1) * 64 + o] = v0.y;
        Wb[(q8 * 8 + 2) * 64 + o] = v0.z; Wb[(q8 * 8 + 3) * 64 + o] = v0.w;
        Wb[(q8 * 8 + 4) * 64 + o] = v1.x; Wb[(q8 * 8 + 5) * 64 + o] = v1.y;
        Wb[(q8 * 8 + 6) * 64 + o] = v1.z; Wb[(q8 * 8 + 7) * 64 + o] = v1.w;
      }
      __syncthreads();
#pragma unroll
      for (int cc = 0; cc < 32; ++cc) {
        float4 wk = *(const float4*)&Wa[cc * 64 + og * 4];
        float4 wv = *(const float4*)&Wb[cc * 64 + og * 4];
        float4 xv = *(const float4*)&Xs[cc * 64 + ng * 4];
        float xs;
        xs = xv.x;
        acck[0].x = fmaf(wk.x, xs, acck[0].x); acck[0].y = fmaf(wk.y, xs, acck[0].y);
        acck[0].z = fmaf(wk.z, xs, acck[0].z); acck[0].w = fmaf(wk.w, xs, acck[0].w);
        accv[0].x = fmaf(wv.x, xs, accv[0].x); accv[0].y = fmaf(wv.y, xs, accv[0].y);
        accv[0].z = fmaf(wv.z, xs, accv[0].z); accv[0].w = fmaf(wv.w, xs, accv[0].w);
        xs = xv.y;
        acck[1].x = fmaf(wk.x, xs, acck[1].x); acck[1].y = fmaf(wk.y, xs, acck[1].y);
        acck[1].z = fmaf(wk.z, xs, acck[1].z); acck[1].w = fmaf(wk.w, xs, acck[1].w);
        accv[1].x = fmaf(wv.x, xs, accv[1].x); accv[1].y = fmaf(wv.y, xs, accv[1].y);
        accv[1].z = fmaf(wv.z, xs, accv[1].z); accv[1].w = fmaf(wv.w, xs, accv[1].w);
        xs = xv.z;
        acck[2].x = fmaf(wk.x, xs, acck[2].x); acck[2].y = fmaf(wk.y, xs, acck[2].y);
        acck[2].z = fmaf(wk.z, xs, acck[2].z); acck[2].w = fmaf(wk.w, xs, acck[2].w);
        accv[2].x = fmaf(wv.x, xs, accv[2].x); accv[2].y = fmaf(wv.y, xs, accv[2].y);
        accv[2].z = fmaf(wv.z, xs, accv[2].z); accv[2].w = fmaf(wv.w, xs, accv[2].w);
        xs = xv.w;
        acck[3].x = fmaf(wk.x, xs, acck[3].x); acck[3].y = fmaf(wk.y, xs, acck[3].y);
        acck[3].z = fmaf(wk.z, xs, acck[3].z); acck[3].w = fmaf(wk.w, xs, acck[3].w);
        accv[3].x = fmaf(wv.x, xs, accv[3].x); accv[3].y = fmaf(wv.y, xs, accv[3].y);
        accv[3].z = fmaf(wv.z, xs, accv[3].z); accv[3].w = fmaf(wv.w, xs, accv[3].w);
      }
      __syncthreads();
    }
    float* outk = ws + OFF_K + (size_t)b * NP * DD;
    float* outv = ws + OFF_V + (size_t)b * NP * DD;
#pragma unroll
    for (int j = 0; j < 4; ++j) {
      *(float4*)&outk[(size_t)(n0 + ng * 4 + j) * DD + og * 4] = acck[j];
      *(float4*)&outv[(size_t)(n0 + ng * 4 + j) * DD + og * 4] = accv[j];
    }
    float s1 = 0.f, s2 = 0.f;
#pragma unroll
    for (int j = 0; j < 4; ++j) {
      s1 += acck[j].x + acck[j].y + acck[j].z + acck[j].w;
      s2 += acck[j].x * acck[j].x + acck[j].y * acck[j].y + acck[j].z * acck[j].z +
            acck[j].w * acck[j].w;
    }
    int g = og >> 1;
    atomicAdd(&sstat[g * 2], s1);
    atomicAdd(&sstat[g * 2 + 1], s2);
    __syncthreads();
    if (tid < 16) atomicAdd(&ws[OFF_STAT + 32 + b * 16 + tid], sstat[tid]);
  }
}

// ---------------------------------------------------------------------------
// Kernel 4: fold GN stats into per-channel affine; transpose Wo
// ---------------------------------------------------------------------------
__global__ void coef_kernel(const float* __restrict__ gqw, const float* __restrict__ gqb,
                            const float* __restrict__ gkw, const float* __restrict__ gkb,
                            const float* __restrict__ Wo, float* __restrict__ ws) {
  int tid = threadIdx.x;
  const float Nf = 8.f * NP;  // elements per (batch, group)
  float* stat = ws + OFF_STAT;
  float* coef = ws + OFF_COEF;
  if (tid < 128) {
    int b = tid >> 6, o = tid & 63, g = o >> 3;
    float s1 = stat[(b * 8 + g) * 2], s2 = stat[(b * 8 + g) * 2 + 1];
    float mu = s1 / Nf;
    float var = s2 / Nf - mu * mu;
    float rstd = rsqrtf(var + 1e-5f);
    coef[tid] = rstd * gqw[o];
    coef[128 + tid] = gqb[o] - mu * rstd * gqw[o];
    s1 = stat[32 + (b * 8 + g) * 2];
    s2 = stat[32 + (b * 8 + g) * 2 + 1];
    mu = s1 / Nf;
    var = s2 / Nf - mu * mu;
    rstd = rsqrtf(var + 1e-5f);
    coef[256 + tid] = rstd * gkw[o];
    coef[384 + tid] = gkb[o] - mu * rstd * gkw[o];
  }
  float* WoT = ws + OFF_WOT;
  for (int i = 0; i < 64; ++i) WoT[i * 256 + tid] = Wo[(size_t)tid * 64 + i];
}

// ---------------------------------------------------------------------------
// Kernel 5: 7x7 local window attention, online softmax.
// New mapping: lane holds float4 of dims (16 lanes cover D=64); the wave's
// four 16-lane groups each own a DIFFERENT query position. Dot-reduce is 4
// shuffles (xor 1,2,4,8 — stays inside the group) serving 4 positions at
// once; exp/softmax state is per-group. K/V loads are dwordx4, 1 KiB/wave.
// grid: B*NP/16 = 1152 blocks, 256 threads (4 waves x 4 positions).
// ---------------------------------------------------------------------------
__global__ __launch_bounds__(256) void attn_kernel(float* __restrict__ ws) {
  int tid = threadIdx.x;
  int lane = tid & 63, widx = tid >> 6;
  int grp = lane >> 4;      // group 0..3 -> position within wave
  int sl = lane & 15;       // slot -> dims 4*sl .. 4*sl+3
  int d0 = sl * 4;
  int pos = blockIdx.x * 16 + widx * 4 + grp;
  int b = pos / NP, n = pos % NP;
  int y = n / WPX, x = n % WPX;
  const float* coef = ws + OFF_COEF;
  float4 aq = *(const float4*)&coef[b * 64 + d0];
  float4 bq = *(const float4*)&coef[128 + b * 64 + d0];
  float4 ak = *(const float4*)&coef[256 + b * 64 + d0];
  float4 bk = *(const float4*)&coef[384 + b * 64 + d0];
  const float* qb = ws + OFF_Q + (size_t)b * NP * DD;
  const float* kb = ws + OFF_K + (size_t)b * NP * DD;
  const float* vb = ws + OFF_V + (size_t)b * NP * DD;
  const float* occl = ws + OFF_OCCL + (size_t)b * NP;
  float4 qv = *(const float4*)&qb[(size_t)n * DD + d0];
  float4 qn;
  qn.x = fmaf(qv.x, aq.x, bq.x);
  qn.y = fmaf(qv.y, aq.y, bq.y);
  qn.z = fmaf(qv.z, aq.z, bq.z);
  qn.w = fmaf(qv.w, aq.w, bq.w);
  float m = -1e30f, l = 0.f;
  float4 acc = make_float4(0.f, 0.f, 0.f, 0.f);
  for (int dy = -3; dy <= 3; ++dy) {
    int yy = y + dy;
    bool rowin = (unsigned)yy < (unsigned)HP;
    for (int dx = -3; dx <= 3; ++dx) {
      int xx = x + dx;
      bool in = rowin && ((unsigned)xx < (unsigned)WPX);
      float logit;
      float4 vv;
      if (in) {  // uniform within the 16-lane group -> shuffles are safe
        int nb = yy * WPX + xx;
        float4 kv = *(const float4*)&kb[(size_t)nb * DD + d0];
        vv = *(const float4*)&vb[(size_t)nb * DD + d0];
        float t;
        t = qn.x * fmaf(kv.x, ak.x, bk.x);
        t = fmaf(qn.y, fmaf(kv.y, ak.y, bk.y), t);
        t = fmaf(qn.z, fmaf(kv.z, ak.z, bk.z), t);
        t = fmaf(qn.w, fmaf(kv.w, ak.w, bk.w), t);
        t += __shfl_xor(t, 1);
        t += __shfl_xor(t, 2);
        t += __shfl_xor(t, 4);
        t += __shfl_xor(t, 8);
        logit = fmaf(t, 0.125f, occl[nb]);
      } else {
        logit = OOB_LOGIT;
        vv = make_float4(0.f, 0.f, 0.f, 0.f);
      }
      float mn = fmaxf(m, logit);
      float cor = __expf(m - mn);
      float wgt = __expf(logit - mn);
      l = fmaf(l, cor, wgt);
      acc.x = fmaf(acc.x, cor, wgt * vv.x);
      acc.y = fmaf(acc.y, cor, wgt * vv.y);
      acc.z = fmaf(acc.z, cor, wgt * vv.z);
      acc.w = fmaf(acc.w, cor, wgt * vv.w);
      m = mn;
    }
  }
  float rl = 1.0f / l;
  float4 o;
  o.x = acc.x * rl;
  o.y = acc.y * rl;
  o.z = acc.z * rl;
  o.w = acc.w * rl;
  *(float4*)&ws[OFF_MSG + ((size_t)b * NP + n) * DD + d0] = o;
}

// ---------------------------------------------------------------------------
// Kernel 6: msgo[b][c][n] = clip(occ,0,1) * sum_d Wo[c][d]*msg[b][n][d]
// grid: B*(NP/32) = 576 blocks, 256 threads (thread owns c = tid, 32 n)
// ---------------------------------------------------------------------------
__global__ __launch_bounds__(256) void wo_kernel(float* __restrict__ ws) {
  __shared__ float Ms[32 * 64];
  __shared__ float T[256 * 33];
  int bid = blockIdx.x;
  int b = bid / (NP / 32);
  int n0 = (bid % (NP / 32)) * 32;
  int tid = threadIdx.x;
  const float* msg = ws + OFF_MSG + ((size_t)b * NP + n0) * DD;
  {
    float4 a0 = *(const float4*)(msg + tid * 8);
    float4 a1 = *(const float4*)(msg + tid * 8 + 4);
    *(float4*)&Ms[tid * 8] = a0;
    *(float4*)&Ms[tid * 8 + 4] = a1;
  }
  __syncthreads();
  const float* WoT = ws + OFF_WOT;
  float acc[32];
#pragma unroll
  for (int n = 0; n < 32; ++n) acc[n] = 0.f;
  for (int dc = 0; dc < 64; dc += 16) {
    float w[16];
#pragma unroll
    for (int i = 0; i < 16; ++i) w[i] = WoT[(size_t)(dc + i) * 256 + tid];
#pragma unroll
    for (int n = 0; n < 32; ++n) {
      const float* mr = &Ms[n * 64 + dc];
      float s = acc[n];
#pragma unroll
      for (int i = 0; i < 16; ++i) s = fmaf(w[i], mr[i], s);
      acc[n] = s;
    }
  }
  const float* occp = ws + OFF_OCCP + (size_t)b * NP + n0;
#pragma unroll
  for (int n = 0; n < 32; ++n) {
    float oc = occp[n];
    oc = fminf(fmaxf(oc, 0.f), 1.f);
    T[tid * 33 + n] = acc[n] * oc;
  }
  __syncthreads();
  float* msgo = ws + OFF_MSGO + (size_t)b * CIMG * NP;
  for (int rep = 0; rep < 32; ++rep) {
    int idx = rep * 256 + tid;
    int c = idx >> 5, n = idx & 31;
    msgo[(size_t)c * NP + n0 + n] = T[c * 33 + n];
  }
}

// ---------------------------------------------------------------------------
// Kernel 7: bilinear x4 upsample (half-pixel) + residual: out = img + a*up(msgo)
// thread handles 4 consecutive x. grid: B*256*384*96/256 = 73728 blocks
// ---------------------------------------------------------------------------
__global__ __launch_bounds__(256) void final_kernel(const float* __restrict__ img,
                                                    const float* __restrict__ ws,
                                                    const float* __restrict__ alpha_p,
                                                    float* __restrict__ out) {
  size_t idx = (size_t)blockIdx.x * 256 + threadIdx.x;
  int xq = (int)(idx % 96);
  size_t t1 = idx / 96;
  int y = (int)(t1 % 384);
  size_t t2 = t1 / 384;
  int c = (int)(t2 % 256);
  int b = (int)(t2 / 256);
  float alpha = *alpha_p;
  const float* mrow = ws + OFF_MSGO + (size_t)(b * 256 + c) * NP;
  float sy = y * 0.25f - 0.375f;
  float jf = floorf(sy);
  float fy = sy - jf;
  int j0 = (int)jf;
  int j1 = j0 + 1;
  j0 = max(j0, 0);
  j1 = min(j1, HP - 1);
  int iL = max(xq - 1, 0), iC = xq, iR = min(xq + 1, WPX - 1);
  const float* r0 = mrow + (size_t)j0 * WPX;
  const float* r1 = mrow + (size_t)j1 * WPX;
  float cL = fmaf(fy, r1[iL] - r0[iL], r0[iL]);
  float cC = fmaf(fy, r1[iC] - r0[iC], r0[iC]);
  float cR = fmaf(fy, r1[iR] - r0[iR], r0[iR]);
  float4 v;
  v.x = fmaf(0.625f, cC - cL, cL);
  v.y = fmaf(0.875f, cC - cL, cL);
  v.z = fmaf(0.125f, cR - cC, cC);
  v.w = fmaf(0.375f, cR - cC, cC);
  size_t base = ((size_t)(b * 256 + c) * 384 + y) * 384 + (size_t)xq * 4;
  float4 im = *(const float4*)(img + base);
  float4 o;
  o.x = fmaf(alpha, v.x, im.x);
  o.y = fmaf(alpha, v.y, im.y);
  o.z = fmaf(alpha, v.z, im.z);
  o.w = fmaf(alpha, v.w, im.w);
  *(float4*)(out + base) = o;
}

// ---------------------------------------------------------------------------
extern "C" void kernel_launch(void* const* d_in, const int* in_sizes, int n_in,
                              void* d_out, int out_size, void* d_ws, size_t ws_size,
                              hipStream_t stream) {
  const float* img = (const float*)d_in[0];
  const float* rad = (const float*)d_in[1];
  const float* occ = (const float*)d_in[2];
  const float* Wq = (const float*)d_in[3];
  const float* Wk = (const float*)d_in[4];
  const float* Wv = (const float*)d_in[5];
  const float* Wo = (const float*)d_in[6];
  const float* gqw = (const float*)d_in[7];
  const float* gqb = (const float*)d_in[8];
  const float* gkw = (const float*)d_in[9];
  const float* gkb = (const float*)d_in[10];
  const float* alpha = (const float*)d_in[11];
  float* ws = (float*)d_ws;
  float* out = (float*)d_out;

  hipMemsetAsync(ws + OFF_STAT, 0, 64 * sizeof(float), stream);
  pool_kernel<<<BB * CIMG + BB * CRAD + BB, 256, 0, stream>>>(img, rad, occ, ws);
  proj_kernel<<<2 * BB * (NP / 64), 256, 0, stream>>>(Wq, Wk, Wv, ws);
  coef_kernel<<<1, 256, 0, stream>>>(gqw, gqb, gkw, gkb, Wo, ws);
  attn_kernel<<<BB * NP / 16, 256, 0, stream>>>(ws);
  wo_kernel<<<BB * (NP / 32), 256, 0, stream>>>(ws);
  final_kernel<<<(BB * 256 * 384 * 96) / 256, 256, 0, stream>>>(img, ws, alpha, out);
}